// Round 14
// baseline (147.832 us; speedup 1.0000x reference)
//
#include <hip/hip_runtime.h>

// PointPillars voxelization, MI355X — round 13 (resubmit; GPU-acquisition
// timeout, never ran): MEASUREMENT round.
// Pipeline is byte-identical to round 12 (114.05us). Two idempotent CLONES
// (scatter3 clone, finalize2 clone) write only to d_ws scratch:
//   dur(r13) - dur(r12) = T(scatter3) + T(finalize2) + 2*dispatch_overhead.
// This decides round 14: big delta -> attack scatter/finalize internals;
// small delta -> consolidate dispatches (overhead-dominated).

constexpr int GXc = 400;
constexpr int GYc = 400;
constexpr int NCELL = GXc * GYc;       // 160000
constexpr int MAXV  = 60000;
constexpr int MAXP  = 32;
constexpr int NF    = 5;

constexpr int SCAN_B = 256;
constexpr int SCAN_E = 8;
constexpr int SCAN_TILE = SCAN_B * SCAN_E;                    // 2048
constexpr int NSCANBLK = (NCELL + SCAN_TILE - 1) / SCAN_TILE; // 79

__device__ __forceinline__ int point_cell(float x, float y, float z) {
    int cx = (int)floorf((x + 50.0f) * 4.0f);
    int cy = (int)floorf((y + 50.0f) * 4.0f);
    int cz = (int)floorf((z + 5.0f) * 0.125f);
    if (cx < 0 || cx >= GXc || cy < 0 || cy >= GYc || cz != 0) return -1;
    return cy * GXc + cx;
}

// Pass 1: occupancy bytes only (no cellId, no atomics).
__global__ void __launch_bounds__(256)
k_bin(const float* __restrict__ pts, int N, unsigned char* __restrict__ occupied) {
    int t = blockIdx.x * blockDim.x + threadIdx.x;
    int i0 = t * 4;
    if (i0 >= N) return;
    if (N - i0 >= 4) {
        const float4* src = (const float4*)(pts + (size_t)i0 * NF);
        float4 q0 = src[0], q1 = src[1], q2 = src[2], q3 = src[3], q4 = src[4];
        float f[20];
        *(float4*)(f + 0)  = q0; *(float4*)(f + 4)  = q1; *(float4*)(f + 8)  = q2;
        *(float4*)(f + 12) = q3; *(float4*)(f + 16) = q4;
        #pragma unroll
        for (int k = 0; k < 4; k++) {
            int c = point_cell(f[k * 5 + 0], f[k * 5 + 1], f[k * 5 + 2]);
            if (c >= 0) occupied[c] = 1;          // benign same-value race
        }
    } else {
        for (int k = 0; k < N - i0; k++) {
            const float* p = pts + (size_t)(i0 + k) * NF;
            int c = point_cell(p[0], p[1], p[2]);
            if (c >= 0) occupied[c] = 1;
        }
    }
}

__global__ void k_scanA(const unsigned char* __restrict__ occupied,
                        int* __restrict__ excl, int* __restrict__ blockSums) {
    __shared__ int sh[SCAN_B];
    int base = blockIdx.x * SCAN_TILE;
    int idx0 = base + threadIdx.x * SCAN_E;
    unsigned long long occ8 = 0;
    if (idx0 < NCELL) occ8 = *(const unsigned long long*)(occupied + idx0);
    int vals[SCAN_E];
    int sum = 0;
    #pragma unroll
    for (int e = 0; e < SCAN_E; e++) {
        int v = (int)((occ8 >> (8 * e)) & 1ull);
        vals[e] = sum;
        sum += v;
    }
    sh[threadIdx.x] = sum;
    __syncthreads();
    for (int off = 1; off < SCAN_B; off <<= 1) {
        int t = (threadIdx.x >= (unsigned)off) ? sh[threadIdx.x - off] : 0;
        __syncthreads();
        sh[threadIdx.x] += t;
        __syncthreads();
    }
    int thrExcl = (threadIdx.x == 0) ? 0 : sh[threadIdx.x - 1];
    #pragma unroll
    for (int e = 0; e < SCAN_E; e++) {
        int idx = idx0 + e;
        if (idx < NCELL) excl[idx] = thrExcl + vals[e];
    }
    if (threadIdx.x == SCAN_B - 1) blockSums[blockIdx.x] = sh[SCAN_B - 1];
}

__global__ void k_scanB(const unsigned char* __restrict__ occupied,
                        const int* __restrict__ excl,
                        const int* __restrict__ blockSums,
                        int* __restrict__ voxId,
                        int* __restrict__ cellOfVox,
                        int* __restrict__ vcount,
                        int* __restrict__ vcount2,
                        int* __restrict__ nvoxOut) {
    __shared__ int sb[128];
    int tid = threadIdx.x;
    if (tid < 128) sb[tid] = (tid < NSCANBLK) ? blockSums[tid] : 0;
    __syncthreads();
    for (int off = 1; off < 128; off <<= 1) {
        int t = (tid < 128 && tid >= off) ? sb[tid - off] : 0;
        __syncthreads();
        if (tid < 128) sb[tid] += t;
        __syncthreads();
    }
    int c = blockIdx.x * blockDim.x + tid;
    if (c < NCELL) {
        int vi = -1;
        if (occupied[c]) {
            int blk = c / SCAN_TILE;
            int basev = (blk == 0) ? 0 : sb[blk - 1];
            int v = basev + excl[c];
            if (v < MAXV) {
                vi = v;
                cellOfVox[v] = c;
                vcount[v] = 0;
                vcount2[v] = 0;                   // clone's counter
            }
        }
        voxId[c] = vi;
    }
    if (blockIdx.x == 0 && tid == 0) {
        int tot = sb[NSCANBLK - 1];
        *nvoxOut = tot < MAXV ? tot : MAXV;
    }
}

// Pass 2: read pts coalesced, recompute cells, write 32B records into vdata.
__global__ void __launch_bounds__(256)
k_scatter3(const float* __restrict__ pts, int N,
           const int* __restrict__ voxId,
           int* __restrict__ vcount, float* __restrict__ vdata) {
    int t = blockIdx.x * blockDim.x + threadIdx.x;
    int i0 = t * 4;
    if (i0 >= N) return;
    if (N - i0 >= 4) {
        const float4* src = (const float4*)(pts + (size_t)i0 * NF);
        float4 q0 = src[0], q1 = src[1], q2 = src[2], q3 = src[3], q4 = src[4];
        float f[20];
        *(float4*)(f + 0)  = q0; *(float4*)(f + 4)  = q1; *(float4*)(f + 8)  = q2;
        *(float4*)(f + 12) = q3; *(float4*)(f + 16) = q4;
        int cs[4];
        #pragma unroll
        for (int k = 0; k < 4; k++)
            cs[k] = point_cell(f[k * 5 + 0], f[k * 5 + 1], f[k * 5 + 2]);
        int vs[4];
        #pragma unroll
        for (int k = 0; k < 4; k++)
            vs[k] = (cs[k] >= 0) ? voxId[cs[k]] : -1;
        #pragma unroll
        for (int k = 0; k < 4; k++) {
            if (vs[k] >= 0) {
                int pos = atomicAdd(&vcount[vs[k]], 1);
                if (pos < MAXP) {
                    float* r = vdata + ((size_t)vs[k] * MAXP + pos) * 8;
                    *(float4*)r = make_float4(f[k*5+0], f[k*5+1], f[k*5+2], f[k*5+3]);
                    *(float4*)(r + 4) = make_float4(f[k*5+4],
                                                    __int_as_float(i0 + k), 0.0f, 0.0f);
                }
            }
        }
    } else {
        for (int k = 0; k < N - i0; k++) {
            const float* p = pts + (size_t)(i0 + k) * NF;
            int c = point_cell(p[0], p[1], p[2]);
            if (c >= 0) {
                int v = voxId[c];
                if (v >= 0) {
                    int pos = atomicAdd(&vcount[v], 1);
                    if (pos < MAXP) {
                        float* r = vdata + ((size_t)v * MAXP + pos) * 8;
                        *(float4*)r = make_float4(p[0], p[1], p[2], p[3]);
                        *(float4*)(r + 4) = make_float4(p[4],
                                                        __int_as_float(i0 + k), 0.0f, 0.0f);
                    }
                }
            }
        }
    }
}

// Finalize: 4 voxels/wave, dense reads, rank-sort by embedded idx, coalesced out.
__global__ void __launch_bounds__(256)
k_finalize2(const int* __restrict__ vcount,
            const float* __restrict__ vdata,
            const int* __restrict__ cellOfVox,
            const int* __restrict__ nvoxPtr,
            float* __restrict__ outVox,
            float* __restrict__ outCoord,
            float* __restrict__ outNum) {
    __shared__ int   s_key[4][4][MAXP];
    __shared__ float s_dat[4][4][MAXP * NF];

    int tid  = threadIdx.x;
    int wv   = tid >> 6, lane = tid & 63;
    int h    = lane >> 5, s = lane & 31;
    int vb   = (blockIdx.x * 4 + wv) * 4;
    int nvox = *nvoxPtr;

    int u0 = vb + h, u1 = vb + 2 + h;
    bool live0 = u0 < nvox, live1 = u1 < nvox;
    int num0 = 0, num1 = 0;
    if (live0) { int cnt = vcount[u0]; num0 = cnt < MAXP ? cnt : MAXP; }
    if (live1) { int cnt = vcount[u1]; num1 = cnt < MAXP ? cnt : MAXP; }
    bool g0 = live0 && s < num0, g1 = live1 && s < num1;

    float4 a0, b0, a1, b1;
    if (g0) {
        const float4* r = (const float4*)(vdata + ((size_t)u0 * MAXP + s) * 8);
        a0 = r[0]; b0 = r[1];
    }
    if (g1) {
        const float4* r = (const float4*)(vdata + ((size_t)u1 * MAXP + s) * 8);
        a1 = r[0]; b1 = r[1];
    }
    int k0 = g0 ? __float_as_int(b0.y) : 0x7fffffff;
    int k1 = g1 ? __float_as_int(b1.y) : 0x7fffffff;
    s_key[wv][h][s]     = k0;
    s_key[wv][2 + h][s] = k1;

    float* flat = (float*)s_dat[wv];
    #pragma unroll
    for (int q = 0; q < 10; q++) flat[q * 64 + lane] = 0.0f;

    int rank0 = 0, rank1 = 0;
    #pragma unroll
    for (int j = 0; j < MAXP; j++) rank0 += (s_key[wv][h][j] < k0) ? 1 : 0;
    #pragma unroll
    for (int j = 0; j < MAXP; j++) rank1 += (s_key[wv][2 + h][j] < k1) ? 1 : 0;
    if (g0) {
        float* d = &s_dat[wv][h][rank0 * NF];
        d[0] = a0.x; d[1] = a0.y; d[2] = a0.z; d[3] = a0.w; d[4] = b0.x;
    }
    if (g1) {
        float* d = &s_dat[wv][2 + h][rank1 * NF];
        d[0] = a1.x; d[1] = a1.y; d[2] = a1.z; d[3] = a1.w; d[4] = b1.x;
    }

    const float4* sv = (const float4*)s_dat[wv];
    float4* dst = (float4*)(outVox + (size_t)vb * (MAXP * NF));
    #pragma unroll
    for (int q = 0; q < 3; q++) {
        int idx = q * 64 + lane;
        if (idx < 160) dst[idx] = sv[idx];
    }
    if (lane < 4) {
        int v = vb + lane;
        bool lv = v < nvox;
        int c = lv ? cellOfVox[v] : 0;
        int cnt = lv ? vcount[v] : 0;
        int num = cnt < MAXP ? cnt : MAXP;
        outNum[v] = lv ? (float)num : 0.0f;
        outCoord[(size_t)v * 3 + 0] = 0.0f;
        outCoord[(size_t)v * 3 + 1] = lv ? (float)(c / GXc) : 0.0f;
        outCoord[(size_t)v * 3 + 2] = lv ? (float)(c % GXc) : 0.0f;
    }
}

extern "C" void kernel_launch(void* const* d_in, const int* in_sizes, int n_in,
                              void* d_out, int out_size, void* d_ws, size_t ws_size,
                              hipStream_t stream) {
    const float* pts = (const float*)d_in[0];
    int N = in_sizes[0] / NF;

    float* out      = (float*)d_out;
    float* outVox   = out;
    float* outCoord = out + (size_t)MAXV * MAXP * NF;
    float* outNum   = outCoord + (size_t)MAXV * 3;

    char* ws = (char*)d_ws;
    auto take = [&](size_t bytes) {
        char* p = ws;
        ws += (bytes + 255) & ~(size_t)255;
        return p;
    };
    unsigned char* occupied = (unsigned char*)take((size_t)NCELL);
    int* vcount    = (int*)take((size_t)MAXV * 4);
    int* excl      = (int*)take((size_t)NCELL * 4);
    int* blockSums = (int*)take((size_t)128 * 4);
    int* voxId     = (int*)take((size_t)NCELL * 4);
    int* cellOfVox = (int*)take((size_t)MAXV * 4);
    float* vdata   = (float*)take((size_t)MAXV * MAXP * 8 * 4);     // 61.4MB
    int* nvoxBuf   = (int*)take(256);
    // ---- clone scratch (measurement only) ----
    int* vcount2   = (int*)take((size_t)MAXV * 4);
    float* vdata2  = (float*)take((size_t)MAXV * MAXP * 8 * 4);     // 61.4MB
    float* outS    = (float*)take((size_t)MAXV * (MAXP * NF + 4) * 4); // 39.4MB
    float* outVox2   = outS;
    float* outCoord2 = outS + (size_t)MAXV * MAXP * NF;
    float* outNum2   = outCoord2 + (size_t)MAXV * 3;

    hipMemsetAsync(occupied, 0, (size_t)NCELL, stream);

    int nb4 = ((N + 3) / 4 + 255) / 256;
    k_bin<<<nb4, 256, 0, stream>>>(pts, N, occupied);
    k_scanA<<<NSCANBLK, SCAN_B, 0, stream>>>(occupied, excl, blockSums);
    k_scanB<<<(NCELL + 255) / 256, 256, 0, stream>>>(occupied, excl, blockSums,
                                                     voxId, cellOfVox, vcount,
                                                     vcount2, nvoxBuf);
    k_scatter3<<<nb4, 256, 0, stream>>>(pts, N, voxId, vcount, vdata);
    // clone A: identical work into scratch
    k_scatter3<<<nb4, 256, 0, stream>>>(pts, N, voxId, vcount2, vdata2);
    k_finalize2<<<MAXV / 16, 256, 0, stream>>>(vcount, vdata, cellOfVox,
                                               nvoxBuf, outVox, outCoord, outNum);
    // clone B: identical work into scratch
    k_finalize2<<<MAXV / 16, 256, 0, stream>>>(vcount2, vdata2, cellOfVox,
                                               nvoxBuf, outVox2, outCoord2, outNum2);
}